// Round 1
// baseline (1453.889 us; speedup 1.0000x reference)
//
#include <hip/hip_runtime.h>

#define F 64

// ---------------- Transform: T = H @ W  (one wave per row) ----------------
__global__ void gcn_transform_kernel(const float* __restrict__ H,
                                     const float* __restrict__ W,
                                     float* __restrict__ T,
                                     int n_nodes) {
    __shared__ float Wl[F * F];  // 16 KiB
    int tid = threadIdx.x;
    // cooperative load of W into LDS (float4)
    for (int i = tid * 4; i < F * F; i += blockDim.x * 4) {
        *(float4*)&Wl[i] = *(const float4*)&W[i];
    }
    __syncthreads();

    int wave = tid >> 6;              // 0..3 for 256-thread block
    int lane = tid & 63;
    int rows_per_block = blockDim.x >> 6;
    for (int r = blockIdx.x * rows_per_block + wave; r < n_nodes;
         r += gridDim.x * rows_per_block) {
        // lane k holds H[r][k]
        float h = H[(size_t)r * F + lane];
        float acc = 0.f;
#pragma unroll
        for (int k = 0; k < F; ++k) {
            float hk = __shfl(h, k, 64);
            // Wl[k*64 + lane]: 64 consecutive floats -> 2 lanes/bank (free)
            acc = fmaf(hk, Wl[k * F + lane], acc);
        }
        T[(size_t)r * F + lane] = acc;
    }
}

// ---------------- Edge scatter: out[row] += val * T[col] ----------------
// 16 threads per edge, each thread owns one float4 (16B) of the 256B row.
__global__ void gcn_edge_kernel(const int* __restrict__ erow,
                                const int* __restrict__ ecol,
                                const float* __restrict__ evals,
                                const float* __restrict__ T,
                                float* __restrict__ out,
                                int n_edges) {
    long long total = (long long)n_edges * 16;
    long long t = (long long)blockIdx.x * blockDim.x + threadIdx.x;
    long long stride = (long long)gridDim.x * blockDim.x;
    for (long long i = t; i < total; i += stride) {
        int e  = (int)(i >> 4);
        int c4 = (int)(i & 15);
        int r = erow[e];
        int c = ecol[e];
        float v = evals[e];
        float4 tv = *(const float4*)&T[(size_t)c * F + c4 * 4];
        float* dst = &out[(size_t)r * F + c4 * 4];
        unsafeAtomicAdd(dst + 0, v * tv.x);
        unsafeAtomicAdd(dst + 1, v * tv.y);
        unsafeAtomicAdd(dst + 2, v * tv.z);
        unsafeAtomicAdd(dst + 3, v * tv.w);
    }
}

// ---------------- Epilogue: out = relu(out + bias) ----------------
__global__ void gcn_epilogue_kernel(float* __restrict__ out,
                                    const float* __restrict__ bias,
                                    long long n) {
    long long t = (long long)blockIdx.x * blockDim.x + threadIdx.x;
    long long stride = (long long)gridDim.x * blockDim.x;
    for (long long i = t; i < n; i += stride) {
        float x = out[i] + bias[i & (F - 1)];
        out[i] = fmaxf(x, 0.f);
    }
}

extern "C" void kernel_launch(void* const* d_in, const int* in_sizes, int n_in,
                              void* d_out, int out_size, void* d_ws, size_t ws_size,
                              hipStream_t stream) {
    const float* H     = (const float*)d_in[0];
    const int*   erow  = (const int*)d_in[1];
    const int*   ecol  = (const int*)d_in[2];
    const float* evals = (const float*)d_in[3];
    const float* W     = (const float*)d_in[4];
    const float* bias  = (const float*)d_in[5];
    float* out = (float*)d_out;
    float* T   = (float*)d_ws;  // n_nodes * 64 floats = 25.6 MB scratch

    int n_nodes = in_sizes[0] / F;
    int n_edges = in_sizes[1];

    // zero the aggregation buffer (harness poisons d_out with 0xAA once)
    hipMemsetAsync(d_out, 0, (size_t)out_size * sizeof(float), stream);

    gcn_transform_kernel<<<1024, 256, 0, stream>>>(H, W, T, n_nodes);
    gcn_edge_kernel<<<4096, 256, 0, stream>>>(erow, ecol, evals, T, out, n_edges);
    gcn_epilogue_kernel<<<2048, 256, 0, stream>>>(out, bias, (long long)out_size);
}

// Round 2
// 449.582 us; speedup vs baseline: 3.2339x; 3.2339x over previous
//
#include <hip/hip_runtime.h>

#define F 64
#define NSCAN 1024

// ---------------- Transform: T = H @ W  (one wave per row) ----------------
__global__ void gcn_transform_kernel(const float* __restrict__ H,
                                     const float* __restrict__ W,
                                     float* __restrict__ T,
                                     int n_nodes) {
    __shared__ float Wl[F * F];  // 16 KiB
    int tid = threadIdx.x;
    for (int i = tid * 4; i < F * F; i += blockDim.x * 4) {
        *(float4*)&Wl[i] = *(const float4*)&W[i];
    }
    __syncthreads();

    int wave = tid >> 6;
    int lane = tid & 63;
    int rows_per_block = blockDim.x >> 6;
    for (int r = blockIdx.x * rows_per_block + wave; r < n_nodes;
         r += gridDim.x * rows_per_block) {
        float h = H[(size_t)r * F + lane];
        float acc = 0.f;
#pragma unroll
        for (int k = 0; k < F; ++k) {
            float hk = __shfl(h, k, 64);
            acc = fmaf(hk, Wl[k * F + lane], acc);
        }
        T[(size_t)r * F + lane] = acc;
    }
}

// ---------------- CSR build step 1: histogram of rows ----------------
__global__ void gcn_hist_kernel(const int* __restrict__ erow,
                                int* __restrict__ counts, int n_edges) {
    int i = blockIdx.x * blockDim.x + threadIdx.x;
    int stride = gridDim.x * blockDim.x;
    for (; i < n_edges; i += stride) atomicAdd(&counts[erow[i]], 1);
}

// ---------------- CSR build step 2: exclusive scan (single block) ----------------
__global__ __launch_bounds__(NSCAN) void gcn_scan_kernel(const int* __restrict__ counts,
                                                         int* __restrict__ row_start,
                                                         int* __restrict__ cursor, int n) {
    __shared__ int wsum[16];
    __shared__ int carry_s;
    int tid = threadIdx.x, lane = tid & 63, wid = tid >> 6;
    if (tid == 0) carry_s = 0;
    __syncthreads();
    for (int base = 0; base < n; base += NSCAN) {
        int i = base + tid;
        int v = (i < n) ? counts[i] : 0;
        int x = v;
#pragma unroll
        for (int d = 1; d < 64; d <<= 1) {
            int y = __shfl_up(x, d, 64);
            if (lane >= d) x += y;
        }
        if (lane == 63) wsum[wid] = x;
        __syncthreads();
        if (tid < 16) {
            int s = wsum[tid];
#pragma unroll
            for (int d = 1; d < 16; d <<= 1) {
                int y = __shfl_up(s, d, 16);
                if (tid >= d) s += y;
            }
            wsum[tid] = s;
        }
        __syncthreads();
        int carry = carry_s;
        int woff = (wid > 0) ? wsum[wid - 1] : 0;
        int excl = carry + woff + (x - v);
        if (i < n) { row_start[i] = excl; cursor[i] = excl; }
        __syncthreads();
        if (tid == 0) carry_s = carry + wsum[15];
        __syncthreads();
    }
    if (tid == 0) row_start[n] = carry_s;
}

// ---------------- CSR build step 3: scatter edges into row-sorted order ----------------
__global__ void gcn_scatter_kernel(const int* __restrict__ erow,
                                   const int* __restrict__ ecol,
                                   const float* __restrict__ evals,
                                   int* __restrict__ cursor,
                                   int* __restrict__ scol,
                                   float* __restrict__ sval, int n_edges) {
    int i = blockIdx.x * blockDim.x + threadIdx.x;
    int stride = gridDim.x * blockDim.x;
    for (; i < n_edges; i += stride) {
        int r = erow[i];
        int pos = atomicAdd(&cursor[r], 1);
        scol[pos] = ecol[i];
        sval[pos] = evals[i];
    }
}

// ---------------- Aggregate: one wave per row, lane = feature; fused bias+relu ----------------
__global__ void gcn_aggregate_kernel(const int* __restrict__ row_start,
                                     const int* __restrict__ scol,
                                     const float* __restrict__ sval,
                                     const float* __restrict__ T,
                                     const float* __restrict__ bias,
                                     float* __restrict__ out, int n_nodes) {
    int lane = threadIdx.x & 63;
    int wid = threadIdx.x >> 6;
    int wpb = blockDim.x >> 6;
    float b = bias[lane];
    for (int r = blockIdx.x * wpb + wid; r < n_nodes; r += gridDim.x * wpb) {
        int s = row_start[r], e = row_start[r + 1];
        float acc = 0.f;
        int j = s;
        int e4 = s + ((e - s) & ~3);
        for (; j < e4; j += 4) {
            int c0 = scol[j], c1 = scol[j + 1], c2 = scol[j + 2], c3 = scol[j + 3];
            float v0 = sval[j], v1 = sval[j + 1], v2 = sval[j + 2], v3 = sval[j + 3];
            float t0 = T[(size_t)c0 * F + lane];
            float t1 = T[(size_t)c1 * F + lane];
            float t2 = T[(size_t)c2 * F + lane];
            float t3 = T[(size_t)c3 * F + lane];
            acc = fmaf(v0, t0, acc);
            acc = fmaf(v1, t1, acc);
            acc = fmaf(v2, t2, acc);
            acc = fmaf(v3, t3, acc);
        }
        for (; j < e; ++j)
            acc = fmaf(sval[j], T[(size_t)scol[j] * F + lane], acc);
        out[(size_t)r * F + lane] = fmaxf(acc + b, 0.f);
    }
}

extern "C" void kernel_launch(void* const* d_in, const int* in_sizes, int n_in,
                              void* d_out, int out_size, void* d_ws, size_t ws_size,
                              hipStream_t stream) {
    const float* H     = (const float*)d_in[0];
    const int*   erow  = (const int*)d_in[1];
    const int*   ecol  = (const int*)d_in[2];
    const float* evals = (const float*)d_in[3];
    const float* W     = (const float*)d_in[4];
    const float* bias  = (const float*)d_in[5];
    float* out = (float*)d_out;

    int n_nodes = in_sizes[0] / F;
    int n_edges = in_sizes[1];

    // workspace layout
    char* ws = (char*)d_ws;
    float* T        = (float*)ws;                       ws += (size_t)n_nodes * F * sizeof(float); // 25.6 MB
    int*  counts    = (int*)ws;                         ws += (size_t)n_nodes * sizeof(int);       // 0.4 MB
    int*  row_start = (int*)ws;                         ws += (size_t)(n_nodes + 1) * sizeof(int); // 0.4 MB
    int*  cursor    = (int*)ws;                         ws += (size_t)n_nodes * sizeof(int);       // 0.4 MB
    int*  scol      = (int*)ws;                         ws += (size_t)n_edges * sizeof(int);       // 6.4 MB
    float* sval     = (float*)ws;                                                                   // 6.4 MB

    hipMemsetAsync(counts, 0, (size_t)n_nodes * sizeof(int), stream);

    gcn_transform_kernel<<<6250, 256, 0, stream>>>(H, W, T, n_nodes);
    gcn_hist_kernel<<<3125, 256, 0, stream>>>(erow, counts, n_edges);
    gcn_scan_kernel<<<1, NSCAN, 0, stream>>>(counts, row_start, cursor, n_nodes);
    gcn_scatter_kernel<<<3125, 256, 0, stream>>>(erow, ecol, evals, cursor, scol, sval, n_edges);
    gcn_aggregate_kernel<<<6250, 256, 0, stream>>>(row_start, scol, sval, T, bias, out, n_nodes);
}

// Round 3
// 359.993 us; speedup vs baseline: 4.0387x; 1.2489x over previous
//
#include <hip/hip_runtime.h>

#define F 64

// ---------------- Transform: T = H @ W  (one wave per row) ----------------
__global__ void gcn_transform_kernel(const float* __restrict__ H,
                                     const float* __restrict__ W,
                                     float* __restrict__ T,
                                     int n_nodes) {
    __shared__ float Wl[F * F];  // 16 KiB
    int tid = threadIdx.x;
    for (int i = tid * 4; i < F * F; i += blockDim.x * 4) {
        *(float4*)&Wl[i] = *(const float4*)&W[i];
    }
    __syncthreads();

    int wave = tid >> 6;
    int lane = tid & 63;
    int rows_per_block = blockDim.x >> 6;
    for (int r = blockIdx.x * rows_per_block + wave; r < n_nodes;
         r += gridDim.x * rows_per_block) {
        float h = H[(size_t)r * F + lane];
        float acc = 0.f;
#pragma unroll
        for (int k = 0; k < F; ++k) {
            float hk = __shfl(h, k, 64);
            acc = fmaf(hk, Wl[k * F + lane], acc);
        }
        T[(size_t)r * F + lane] = acc;
    }
}

// ---------------- CSR build step 1: histogram of rows (4 edges/thread) ----------------
__global__ void gcn_hist_kernel(const int* __restrict__ erow,
                                int* __restrict__ counts, int n_edges) {
    int i = (blockIdx.x * blockDim.x + threadIdx.x) * 4;
    if (i + 3 < n_edges) {
        int4 r = *(const int4*)&erow[i];
        atomicAdd(&counts[r.x], 1);
        atomicAdd(&counts[r.y], 1);
        atomicAdd(&counts[r.z], 1);
        atomicAdd(&counts[r.w], 1);
    } else {
        for (; i < n_edges; ++i) atomicAdd(&counts[erow[i]], 1);
    }
}

// ---------------- Scan phase 1: per-block (1024 elems) exclusive scan + block sum ----------------
__global__ __launch_bounds__(256) void gcn_scan1_kernel(const int* __restrict__ counts,
                                                        int* __restrict__ row_start,
                                                        int* __restrict__ bsum, int n) {
    __shared__ int wsum[4];
    int tid = threadIdx.x, lane = tid & 63, wid = tid >> 6;
    int base = blockIdx.x * 1024 + tid * 4;
    int a0 = 0, a1 = 0, a2 = 0, a3 = 0;
    if (base + 3 < n) {
        int4 v = *(const int4*)&counts[base];
        a0 = v.x; a1 = v.y; a2 = v.z; a3 = v.w;
    } else if (base < n) {
        a0 = counts[base];
        if (base + 1 < n) a1 = counts[base + 1];
        if (base + 2 < n) a2 = counts[base + 2];
    }
    int t = a0 + a1 + a2 + a3;
    int x = t;
#pragma unroll
    for (int d = 1; d < 64; d <<= 1) {
        int y = __shfl_up(x, d, 64);
        if (lane >= d) x += y;
    }
    if (lane == 63) wsum[wid] = x;
    __syncthreads();
    int woff = 0;
    if (wid >= 1) woff += wsum[0];
    if (wid >= 2) woff += wsum[1];
    if (wid >= 3) woff += wsum[2];
    int excl = woff + x - t;
    if (base + 3 < n) {
        int4 o;
        o.x = excl; o.y = excl + a0; o.z = excl + a0 + a1; o.w = excl + a0 + a1 + a2;
        *(int4*)&row_start[base] = o;
    } else if (base < n) {
        row_start[base] = excl;
        if (base + 1 < n) row_start[base + 1] = excl + a0;
        if (base + 2 < n) row_start[base + 2] = excl + a0 + a1;
    }
    if (tid == 255) bsum[blockIdx.x] = woff + x;
}

// ---------------- Scan phase 2: single block scans the block sums ----------------
__global__ __launch_bounds__(256) void gcn_scan2_kernel(int* __restrict__ bsum,
                                                        int* __restrict__ total_out, int nb) {
    __shared__ int wsum[4];
    int tid = threadIdx.x, lane = tid & 63, wid = tid >> 6;
    int v = (tid < nb) ? bsum[tid] : 0;
    int x = v;
#pragma unroll
    for (int d = 1; d < 64; d <<= 1) {
        int y = __shfl_up(x, d, 64);
        if (lane >= d) x += y;
    }
    if (lane == 63) wsum[wid] = x;
    __syncthreads();
    int woff = 0;
    if (wid >= 1) woff += wsum[0];
    if (wid >= 2) woff += wsum[1];
    if (wid >= 3) woff += wsum[2];
    if (tid < nb) bsum[tid] = woff + x - v;
    if (tid == 255) total_out[0] = woff + x;
}

// ---------------- Scan phase 3: add block offsets, produce cursor copy ----------------
__global__ __launch_bounds__(256) void gcn_scan3_kernel(int* __restrict__ row_start,
                                                        int* __restrict__ cursor,
                                                        const int* __restrict__ bsum, int n) {
    int off = bsum[blockIdx.x];
    int base = blockIdx.x * 1024 + threadIdx.x * 4;
    if (base + 3 < n) {
        int4 v = *(const int4*)&row_start[base];
        v.x += off; v.y += off; v.z += off; v.w += off;
        *(int4*)&row_start[base] = v;
        *(int4*)&cursor[base] = v;
    } else if (base < n) {
        for (int i = base; i < n && i < base + 4; ++i) {
            int v = row_start[i] + off;
            row_start[i] = v;
            cursor[i] = v;
        }
    }
}

// ---------------- Scatter: packed (col,val) 8B records into row-sorted order ----------------
__global__ void gcn_scatter_kernel(const int* __restrict__ erow,
                                   const int* __restrict__ ecol,
                                   const float* __restrict__ evals,
                                   int* __restrict__ cursor,
                                   int2* __restrict__ srec, int n_edges) {
    int i = (blockIdx.x * blockDim.x + threadIdx.x) * 4;
    if (i + 3 < n_edges) {
        int4 r = *(const int4*)&erow[i];
        int4 c = *(const int4*)&ecol[i];
        float4 v = *(const float4*)&evals[i];
        int p0 = atomicAdd(&cursor[r.x], 1);
        int p1 = atomicAdd(&cursor[r.y], 1);
        int p2 = atomicAdd(&cursor[r.z], 1);
        int p3 = atomicAdd(&cursor[r.w], 1);
        srec[p0] = make_int2(c.x, __float_as_int(v.x));
        srec[p1] = make_int2(c.y, __float_as_int(v.y));
        srec[p2] = make_int2(c.z, __float_as_int(v.z));
        srec[p3] = make_int2(c.w, __float_as_int(v.w));
    } else {
        for (; i < n_edges; ++i) {
            int pos = atomicAdd(&cursor[erow[i]], 1);
            srec[pos] = make_int2(ecol[i], __float_as_int(evals[i]));
        }
    }
}

// ---------------- Aggregate: one wave per row, lane = feature; fused bias+relu ----------------
__global__ void gcn_aggregate_kernel(const int* __restrict__ row_start,
                                     const int2* __restrict__ srec,
                                     const float* __restrict__ T,
                                     const float* __restrict__ bias,
                                     float* __restrict__ out, int n_nodes) {
    int lane = threadIdx.x & 63;
    int wid = threadIdx.x >> 6;
    int wpb = blockDim.x >> 6;
    float b = bias[lane];
    for (int r = blockIdx.x * wpb + wid; r < n_nodes; r += gridDim.x * wpb) {
        int s = row_start[r], e = row_start[r + 1];
        float acc = 0.f;
        int j = s;
        int e4 = s + ((e - s) & ~3);
        for (; j < e4; j += 4) {
            int2 r0 = srec[j], r1 = srec[j + 1], r2 = srec[j + 2], r3 = srec[j + 3];
            float t0 = T[(size_t)r0.x * F + lane];
            float t1 = T[(size_t)r1.x * F + lane];
            float t2 = T[(size_t)r2.x * F + lane];
            float t3 = T[(size_t)r3.x * F + lane];
            acc = fmaf(__int_as_float(r0.y), t0, acc);
            acc = fmaf(__int_as_float(r1.y), t1, acc);
            acc = fmaf(__int_as_float(r2.y), t2, acc);
            acc = fmaf(__int_as_float(r3.y), t3, acc);
        }
        for (; j < e; ++j) {
            int2 rc = srec[j];
            acc = fmaf(__int_as_float(rc.y), T[(size_t)rc.x * F + lane], acc);
        }
        out[(size_t)r * F + lane] = fmaxf(acc + b, 0.f);
    }
}

extern "C" void kernel_launch(void* const* d_in, const int* in_sizes, int n_in,
                              void* d_out, int out_size, void* d_ws, size_t ws_size,
                              hipStream_t stream) {
    const float* H     = (const float*)d_in[0];
    const int*   erow  = (const int*)d_in[1];
    const int*   ecol  = (const int*)d_in[2];
    const float* evals = (const float*)d_in[3];
    const float* W     = (const float*)d_in[4];
    const float* bias  = (const float*)d_in[5];
    float* out = (float*)d_out;

    int n_nodes = in_sizes[0] / F;
    int n_edges = in_sizes[1];
    int nb = (n_nodes + 1023) / 1024;  // scan blocks

    // workspace layout (all chunks 16B-aligned)
    char* ws = (char*)d_ws;
    float* T        = (float*)ws;  ws += (size_t)n_nodes * F * sizeof(float);   // 25.6 MB
    int2*  srec     = (int2*)ws;   ws += (size_t)n_edges * sizeof(int2);        // 12.8 MB
    int*   counts   = (int*)ws;    ws += (size_t)n_nodes * sizeof(int);         // 0.4 MB
    int*   row_start= (int*)ws;    ws += (size_t)(n_nodes + 4) * sizeof(int);   // 0.4 MB
    int*   cursor   = (int*)ws;    ws += (size_t)n_nodes * sizeof(int);         // 0.4 MB
    int*   bsum     = (int*)ws;                                                  // small

    hipMemsetAsync(counts, 0, (size_t)n_nodes * sizeof(int), stream);

    gcn_transform_kernel<<<6250, 256, 0, stream>>>(H, W, T, n_nodes);
    gcn_hist_kernel<<<(n_edges / 4 + 255) / 256, 256, 0, stream>>>(erow, counts, n_edges);
    gcn_scan1_kernel<<<nb, 256, 0, stream>>>(counts, row_start, bsum, n_nodes);
    gcn_scan2_kernel<<<1, 256, 0, stream>>>(bsum, &row_start[n_nodes], nb);
    gcn_scan3_kernel<<<nb, 256, 0, stream>>>(row_start, cursor, bsum, n_nodes);
    gcn_scatter_kernel<<<(n_edges / 4 + 255) / 256, 256, 0, stream>>>(erow, ecol, evals, cursor, srec, n_edges);
    gcn_aggregate_kernel<<<6250, 256, 0, stream>>>(row_start, srec, T, bias, out, n_nodes);
}